// Round 2
// baseline (303.380 us; speedup 1.0000x reference)
//
#include <hip/hip_runtime.h>
#include <hip/hip_bf16.h>
#include <stdint.h>

typedef float  f32x4  __attribute__((ext_vector_type(4)));
typedef __bf16 bf16x8 __attribute__((ext_vector_type(8)));
typedef __bf16 bf16x4 __attribute__((ext_vector_type(4)));

static constexpr int NB = 8, NS = 1024, NE = 1024, NH = 16;

#define MFMA16(a, b, c) __builtin_amdgcn_mfma_f32_16x16x32_bf16((a), (b), (c), 0, 0, 0)

__device__ __forceinline__ void gload_lds16(const void* g, void* l) {
    __builtin_amdgcn_global_load_lds(
        (const __attribute__((address_space(1))) void*)g,
        (__attribute__((address_space(3))) void*)l, 16, 0, 0);
}

// ---------------------------------------------------------------------------
// Kernel 1: proj = cos(x + theta), dual layout (see round 0).
// ---------------------------------------------------------------------------
__global__ __launch_bounds__(256) void k_proj(const float* __restrict__ x,
                                              const float* __restrict__ theta,
                                              __bf16* __restrict__ proj,
                                              __bf16* __restrict__ projT) {
    __shared__ float sm[64][65];
    const int bid  = blockIdx.x;
    const int bh   = bid >> 4;
    const int st0  = (bid & 15) << 6;
    const int b    = bh >> 4, h = bh & 15;
    const int t    = threadIdx.x;
    const int srow = t >> 2;
    const int j4   = t & 3;

    const float* xrow = x + ((size_t)(b * NS + st0 + srow)) * NE + h * 64;
    __bf16* prow = proj + ((size_t)bh * NS + st0 + srow) * 64;

#pragma unroll
    for (int k = 0; k < 4; ++k) {
        const int d = k * 16 + j4 * 4;
        float4 xv = *(const float4*)(xrow + d);
        float4 tv = *(const float4*)(theta + d);
        float c0 = __cosf(xv.x + tv.x);
        float c1 = __cosf(xv.y + tv.y);
        float c2 = __cosf(xv.z + tv.z);
        float c3 = __cosf(xv.w + tv.w);
        bf16x4 pv = {(__bf16)c0, (__bf16)c1, (__bf16)c2, (__bf16)c3};
        *(bf16x4*)(prow + d) = pv;
        sm[d + 0][srow] = c0;
        sm[d + 1][srow] = c1;
        sm[d + 2][srow] = c2;
        sm[d + 3][srow] = c3;
    }
    __syncthreads();

    const int drow = t >> 2;
    bf16x8 o0, o1;
#pragma unroll
    for (int i = 0; i < 8; ++i) {
        o0[i] = (__bf16)sm[drow][j4 * 16 + i];
        o1[i] = (__bf16)sm[drow][j4 * 16 + 8 + i];
    }
    __bf16* dst = projT + ((size_t)bh * 64 + drow) * NS + st0 + j4 * 16;
    *(bf16x8*)dst = o0;
    *(bf16x8*)(dst + 8) = o1;
}

// ---------------------------------------------------------------------------
// Kernel 2: W (f32 [E,E]) -> bf16
// ---------------------------------------------------------------------------
__global__ __launch_bounds__(256) void k_cvtW(const float* __restrict__ W,
                                              __bf16* __restrict__ Wb) {
    const int i = (blockIdx.x * 256 + threadIdx.x) * 4;
    float4 v = *(const float4*)(W + i);
    bf16x4 o = {(__bf16)v.x, (__bf16)v.y, (__bf16)v.z, (__bf16)v.w};
    *(bf16x4*)(Wb + i) = o;
}

// ---------------------------------------------------------------------------
// Kernel 3: flash attention, Q=K=V=proj, FIXED-SHIFT softmax.
// |scores| <= 64/sqrt(64) = 8  =>  exp2-domain max <= 8*log2e = 11.5416.
// p = exp2(s*csc - 11.5416) in [2^-23.1, 1]; softmax is shift-invariant so
// the result is mathematically identical to max-shifted softmax, with no
// online rescaling needed. lsum is accumulated per-lane, reduced once at end.
// ---------------------------------------------------------------------------
__global__ __launch_bounds__(256) void k_attn(const __bf16* __restrict__ proj,
                                              const __bf16* __restrict__ projT,
                                              __bf16* __restrict__ attn_out) {
    __shared__ float ep[4][16][69];

    const int bid  = blockIdx.x;
    const int bh   = bid >> 4;
    const int qt   = bid & 15;
    const int t    = threadIdx.x;
    const int w    = t >> 6;
    const int lane = t & 63;
    const int g    = lane >> 4;
    const int c    = lane & 15;
    const int qbase = qt * 64 + w * 16;

    const __bf16* P  = proj  + (size_t)bh * NS * 64;
    const __bf16* PT = projT + (size_t)bh * 64 * NS;

    bf16x8 bq0 = *(const bf16x8*)(P + (size_t)(qbase + c) * 64 + g * 8);
    bf16x8 bq1 = *(const bf16x8*)(P + (size_t)(qbase + c) * 64 + 32 + g * 8);

    f32x4 acc[4];
#pragma unroll
    for (int dc = 0; dc < 4; ++dc) acc[dc] = (f32x4){0.f, 0.f, 0.f, 0.f};
    float rs_acc = 0.f;
    const float csc = 0.18033688f;   // (1/sqrt(64)) * log2(e)
    const float SMC = 11.5415606f;   // 8 * log2(e): provable score bound

    const int s0l = (((2 * g) & 3) << 4) | c;
    const int s1l = (((2 * g + 1) & 3) << 4) | c;
    const uint32_t psel = (g < 2) ? 0x05040100u : 0x07060302u;

#pragma unroll 2
    for (int kv = 0; kv < NS; kv += 32) {
        const __bf16* Kp = P + (size_t)kv * 64;
        bf16x8 ak00 = *(const bf16x8*)(Kp + (size_t)c * 64 + g * 8);
        bf16x8 ak01 = *(const bf16x8*)(Kp + (size_t)c * 64 + 32 + g * 8);
        bf16x8 ak10 = *(const bf16x8*)(Kp + (size_t)(16 + c) * 64 + g * 8);
        bf16x8 ak11 = *(const bf16x8*)(Kp + (size_t)(16 + c) * 64 + 32 + g * 8);

        f32x4 st0 = (f32x4){0.f, 0.f, 0.f, 0.f};
        f32x4 st1 = (f32x4){0.f, 0.f, 0.f, 0.f};
        __builtin_amdgcn_s_setprio(1);
        st0 = MFMA16(ak00, bq0, st0);
        st0 = MFMA16(ak01, bq1, st0);
        st1 = MFMA16(ak10, bq0, st1);
        st1 = MFMA16(ak11, bq1, st1);
        __builtin_amdgcn_s_setprio(0);

        // p = exp2(s*csc - SMC); accumulate row-sum per lane (no shuffles here)
        float p0[4], p1[4];
#pragma unroll
        for (int r = 0; r < 4; ++r) {
            p0[r] = exp2f(fmaf(st0[r], csc, -SMC));
            p1[r] = exp2f(fmaf(st1[r], csc, -SMC));
            rs_acc += p0[r] + p1[r];
        }

        // Pack (bf16(p0), bf16(p1)) -> u32, shuffle once, select+pair via v_perm.
        union PK { __bf16 h[2]; uint32_t u; };
        uint32_t u0[4], u1[4];
#pragma unroll
        for (int r = 0; r < 4; ++r) {
            PK pk;
            pk.h[0] = (__bf16)p0[r];
            pk.h[1] = (__bf16)p1[r];
            u0[r] = (uint32_t)__shfl((int)pk.u, s0l);
            u1[r] = (uint32_t)__shfl((int)pk.u, s1l);
        }
        union PB { uint32_t u[4]; bf16x8 v; } pb;
        pb.u[0] = __builtin_amdgcn_perm(u0[1], u0[0], psel);
        pb.u[1] = __builtin_amdgcn_perm(u0[3], u0[2], psel);
        pb.u[2] = __builtin_amdgcn_perm(u1[1], u1[0], psel);
        pb.u[3] = __builtin_amdgcn_perm(u1[3], u1[2], psel);

        // PV: out^T[d, q] += V^T[d, k] * P^T[k, q]
        __builtin_amdgcn_s_setprio(1);
#pragma unroll
        for (int dc = 0; dc < 4; ++dc) {
            bf16x8 av = *(const bf16x8*)(PT + (size_t)(dc * 16 + c) * NS + kv + g * 8);
            acc[dc] = MFMA16(av, pb.v, acc[dc]);
        }
        __builtin_amdgcn_s_setprio(0);
    }

    // One cross-lane lsum reduce at the very end.
    rs_acc += __shfl_xor(rs_acc, 16);
    rs_acc += __shfl_xor(rs_acc, 32);
    const float inv = 1.0f / rs_acc;

#pragma unroll
    for (int dc = 0; dc < 4; ++dc) {
#pragma unroll
        for (int r = 0; r < 4; ++r)
            ep[w][c][dc * 16 + 4 * g + r] = acc[dc][r] * inv;
    }
    __syncthreads();

    const int orow = lane >> 2;
    const int och  = lane & 3;
    bf16x8 o0, o1;
#pragma unroll
    for (int i = 0; i < 8; ++i) {
        o0[i] = (__bf16)ep[w][orow][och * 16 + i];
        o1[i] = (__bf16)ep[w][orow][och * 16 + 8 + i];
    }
    __bf16* dst = attn_out +
        ((size_t)(bh >> 4) * NS + qt * 64 + w * 16 + orow) * NE + (bh & 15) * 64 + och * 16;
    *(bf16x8*)dst = o0;
    *(bf16x8*)(dst + 8) = o1;
}

// ---------------------------------------------------------------------------
// Kernel 4: C[M,N] = A[M,K](bf16) x W^T   (m97 structure, 128x128, BK=32)
// ---------------------------------------------------------------------------
__global__ __launch_bounds__(256) void k_gemm(const __bf16* __restrict__ A,
                                              const __bf16* __restrict__ Bw,
                                              float* __restrict__ C) {
    constexpr int K = 1024, N = 1024;
    __shared__ __bf16 As[128 * 32];
    __shared__ __bf16 Bs[128 * 32];

    const int t = threadIdx.x;
    const int lane = t & 63, w = t >> 6;
    const int g = lane >> 4, c = lane & 15;
    const int wr = w >> 1, wc = w & 1;
    const size_t row0 = (size_t)blockIdx.x * 128;
    const size_t col0 = (size_t)blockIdx.y * 128;

    const char* Ag = (const char*)(A + row0 * K);
    const char* Bg = (const char*)(Bw + col0 * K);
    char* AsB = (char*)As;
    char* BsB = (char*)Bs;
    const int srow  = t >> 2;
    const int sbyte = (t & 3) * 16;

    f32x4 acc[4][4];
#pragma unroll
    for (int m = 0; m < 4; ++m)
#pragma unroll
        for (int n = 0; n < 4; ++n) acc[m][n] = (f32x4){0.f, 0.f, 0.f, 0.f};

    for (int kb = 0; kb < K; kb += 32) {
        gload_lds16(Ag + (size_t)srow * (K * 2) + kb * 2 + sbyte, AsB + t * 16);
        gload_lds16(Ag + (size_t)(srow + 64) * (K * 2) + kb * 2 + sbyte, AsB + 4096 + t * 16);
        gload_lds16(Bg + (size_t)srow * (K * 2) + kb * 2 + sbyte, BsB + t * 16);
        gload_lds16(Bg + (size_t)(srow + 64) * (K * 2) + kb * 2 + sbyte, BsB + 4096 + t * 16);
        __syncthreads();

        bf16x8 a[4], b[4];
#pragma unroll
        for (int m = 0; m < 4; ++m)
            a[m] = *(const bf16x8*)(As + (wr * 64 + m * 16 + c) * 32 + g * 8);
#pragma unroll
        for (int n = 0; n < 4; ++n)
            b[n] = *(const bf16x8*)(Bs + (wc * 64 + n * 16 + c) * 32 + g * 8);
#pragma unroll
        for (int m = 0; m < 4; ++m)
#pragma unroll
            for (int n = 0; n < 4; ++n) acc[m][n] = MFMA16(a[m], b[n], acc[m][n]);
        __syncthreads();
    }

#pragma unroll
    for (int m = 0; m < 4; ++m)
#pragma unroll
        for (int n = 0; n < 4; ++n)
#pragma unroll
            for (int r = 0; r < 4; ++r)
                C[(row0 + wr * 64 + m * 16 + 4 * g + r) * N + col0 + wc * 64 + n * 16 + c] =
                    acc[m][n][r];
}

// ---------------------------------------------------------------------------
extern "C" void kernel_launch(void* const* d_in, const int* in_sizes, int n_in,
                              void* d_out, int out_size, void* d_ws, size_t ws_size,
                              hipStream_t stream) {
    const float* x     = (const float*)d_in[0];
    const float* theta = (const float*)d_in[1];
    const float* W     = (const float*)d_in[2];
    float* out = (float*)d_out;

    char* ws = (char*)d_ws;
    __bf16* proj  = (__bf16*)(ws);
    __bf16* projT = (__bf16*)(ws + 16777216);
    __bf16* Wb    = (__bf16*)(ws + 33554432);
    __bf16* ao    = (__bf16*)(ws + 35651584);

    k_proj<<<NB * NH * (NS / 64), 256, 0, stream>>>(x, theta, proj, projT);
    k_cvtW<<<(NE * NE / 4) / 256, 256, 0, stream>>>(W, Wb);
    k_attn<<<NB * NH * (NS / 64), 256, 0, stream>>>(proj, projT, ao);
    dim3 gg(NB * NS / 128, NE / 128);
    k_gemm<<<gg, 256, 0, stream>>>(ao, Wb, out);
}

// Round 3
// 123.005 us; speedup vs baseline: 2.4664x; 2.4664x over previous
//
#include <hip/hip_runtime.h>
#include <hip/hip_bf16.h>
#include <stdint.h>

typedef float  f32x4  __attribute__((ext_vector_type(4)));
typedef __bf16 bf16x8 __attribute__((ext_vector_type(8)));
typedef __bf16 bf16x4 __attribute__((ext_vector_type(4)));

static constexpr int NB = 8, NS = 1024, NE = 1024, NH = 16;

#define MFMA16(a, b, c) __builtin_amdgcn_mfma_f32_16x16x32_bf16((a), (b), (c), 0, 0, 0)

__device__ __forceinline__ void gload_lds16(const void* g, void* l) {
    __builtin_amdgcn_global_load_lds(
        (const __attribute__((address_space(1))) void*)g,
        (__attribute__((address_space(3))) void*)l, 16, 0, 0);
}

// ---------------------------------------------------------------------------
// Kernel 1: proj = cos(x + theta), dual layout.
// ---------------------------------------------------------------------------
__global__ __launch_bounds__(256) void k_proj(const float* __restrict__ x,
                                              const float* __restrict__ theta,
                                              __bf16* __restrict__ proj,
                                              __bf16* __restrict__ projT) {
    __shared__ float sm[64][65];
    const int bid  = blockIdx.x;
    const int bh   = bid >> 4;
    const int st0  = (bid & 15) << 6;
    const int b    = bh >> 4, h = bh & 15;
    const int t    = threadIdx.x;
    const int srow = t >> 2;
    const int j4   = t & 3;

    const float* xrow = x + ((size_t)(b * NS + st0 + srow)) * NE + h * 64;
    __bf16* prow = proj + ((size_t)bh * NS + st0 + srow) * 64;

#pragma unroll
    for (int k = 0; k < 4; ++k) {
        const int d = k * 16 + j4 * 4;
        float4 xv = *(const float4*)(xrow + d);
        float4 tv = *(const float4*)(theta + d);
        float c0 = __cosf(xv.x + tv.x);
        float c1 = __cosf(xv.y + tv.y);
        float c2 = __cosf(xv.z + tv.z);
        float c3 = __cosf(xv.w + tv.w);
        bf16x4 pv = {(__bf16)c0, (__bf16)c1, (__bf16)c2, (__bf16)c3};
        *(bf16x4*)(prow + d) = pv;
        sm[d + 0][srow] = c0;
        sm[d + 1][srow] = c1;
        sm[d + 2][srow] = c2;
        sm[d + 3][srow] = c3;
    }
    __syncthreads();

    const int drow = t >> 2;
    bf16x8 o0, o1;
#pragma unroll
    for (int i = 0; i < 8; ++i) {
        o0[i] = (__bf16)sm[drow][j4 * 16 + i];
        o1[i] = (__bf16)sm[drow][j4 * 16 + 8 + i];
    }
    __bf16* dst = projT + ((size_t)bh * 64 + drow) * NS + st0 + j4 * 16;
    *(bf16x8*)dst = o0;
    *(bf16x8*)(dst + 8) = o1;
}

// ---------------------------------------------------------------------------
// Kernel 2: W (f32 [E,E]) -> bf16
// ---------------------------------------------------------------------------
__global__ __launch_bounds__(256) void k_cvtW(const float* __restrict__ W,
                                              __bf16* __restrict__ Wb) {
    const int i = (blockIdx.x * 256 + threadIdx.x) * 4;
    float4 v = *(const float4*)(W + i);
    bf16x4 o = {(__bf16)v.x, (__bf16)v.y, (__bf16)v.z, (__bf16)v.w};
    *(bf16x4*)(Wb + i) = o;
}

// ---------------------------------------------------------------------------
// Kernel 3: flash attention, LDS-staged K/V with XOR swizzle, dbuf, KVBLK=64.
//   K tile [64 rows][64 d] bf16 (128B rows), V^T tile [64 d][64 kv] bf16.
//   Swizzle: 16B-chunk index cc stored at cc ^ (row&7); achieved by
//   pre-swizzling the per-lane GLOBAL source (LDS dest stays linear, rule 21),
//   reads use swizzled ds_read_b128 -> conflict-free (2-way max).
//   Softmax: fixed-shift exp2 (|scores| <= 8 provable since proj = cos).
// ---------------------------------------------------------------------------
__global__ __launch_bounds__(256) void k_attn(const __bf16* __restrict__ proj,
                                              const __bf16* __restrict__ projT,
                                              __bf16* __restrict__ attn_out) {
    __shared__ __align__(16) char smem[32768];
    // dbuf: K at 0 / 16K, V at 8K / 24K; epilogue reuses smem after the loop.
    __bf16* const smK0 = (__bf16*)(smem);
    __bf16* const smV0 = (__bf16*)(smem + 8192);
    __bf16* const smK1 = (__bf16*)(smem + 16384);
    __bf16* const smV1 = (__bf16*)(smem + 24576);
    float* const ep = (float*)smem;  // [4][16][69]

    const int bid  = blockIdx.x;
    const int bh   = bid >> 4;
    const int qt   = bid & 15;
    const int t    = threadIdx.x;
    const int w    = t >> 6;
    const int lane = t & 63;
    const int g    = lane >> 4;    // 0..3
    const int c    = lane & 15;    // 0..15
    const int c7   = c & 7;
    const int qbase = qt * 64 + w * 16;

    const __bf16* P  = proj  + (size_t)bh * NS * 64;
    const __bf16* PT = projT + (size_t)bh * 64 * NS;

    // Q fragments (B operand): lane holds Q[q=c][d = 32*hf + 8g + i]
    bf16x8 bq0 = *(const bf16x8*)(P + (size_t)(qbase + c) * 64 + g * 8);
    bf16x8 bq1 = *(const bf16x8*)(P + (size_t)(qbase + c) * 64 + 32 + g * 8);

    // Staging geometry: thread t, pass p covers LDS row r = p*32 + (t>>3),
    // dest chunk j = t&7; source chunk = j ^ (r&7) = (t&7) ^ ((t>>3)&7).
    const int srow  = t >> 3;                       // 0..31
    const int sjsrc = (t & 7) ^ (srow & 7);         // pre-swizzled chunk
    char* const dK0 = (char*)smK0 + t * 16;
    char* const dV0 = (char*)smV0 + t * 16;
    char* const dK1 = (char*)smK1 + t * 16;
    char* const dV1 = (char*)smV1 + t * 16;

#define STAGE(kvoff, dk, dv)                                                     \
    do {                                                                         \
        gload_lds16(P  + (size_t)((kvoff) + srow)      * 64 + sjsrc * 8, (dk));  \
        gload_lds16(P  + (size_t)((kvoff) + 32 + srow) * 64 + sjsrc * 8, (dk) + 4096); \
        gload_lds16(PT + (size_t)srow        * NS + (kvoff) + sjsrc * 8, (dv));  \
        gload_lds16(PT + (size_t)(32 + srow) * NS + (kvoff) + sjsrc * 8, (dv) + 4096); \
    } while (0)

    f32x4 acc[4];
#pragma unroll
    for (int dc = 0; dc < 4; ++dc) acc[dc] = (f32x4){0.f, 0.f, 0.f, 0.f};
    float rs_acc = 0.f;
    const float csc = 0.18033688f;   // (1/sqrt(64)) * log2(e)
    const float SMC = 11.5415606f;   // 8 * log2(e): provable score bound

    const int s0l = (((2 * g) & 3) << 4) | c;
    const int s1l = (((2 * g + 1) & 3) << 4) | c;
    const uint32_t psel = (g < 2) ? 0x05040100u : 0x07060302u;

    STAGE(0, dK0, dV0);
    __syncthreads();

    for (int it = 0; it < 16; ++it) {
        const int cur = it & 1;
        const __bf16* sK = cur ? smK1 : smK0;
        const __bf16* sV = cur ? smV1 : smV0;
        if (it < 15) {
            if (cur) STAGE((it + 1) * 64, dK0, dV0);
            else     STAGE((it + 1) * 64, dK1, dV1);
        }

#pragma unroll
        for (int ch = 0; ch < 2; ++ch) {   // two 32-row score chunks
            // K fragments from LDS (swizzled read)
            const int t0 = ch * 2, t1 = ch * 2 + 1;
            bf16x8 ak00 = *(const bf16x8*)(sK + (t0 * 16 + c) * 64 + ((g)     ^ c7) * 8);
            bf16x8 ak01 = *(const bf16x8*)(sK + (t0 * 16 + c) * 64 + ((4 + g) ^ c7) * 8);
            bf16x8 ak10 = *(const bf16x8*)(sK + (t1 * 16 + c) * 64 + ((g)     ^ c7) * 8);
            bf16x8 ak11 = *(const bf16x8*)(sK + (t1 * 16 + c) * 64 + ((4 + g) ^ c7) * 8);

            f32x4 st0 = (f32x4){0.f, 0.f, 0.f, 0.f};
            f32x4 st1 = (f32x4){0.f, 0.f, 0.f, 0.f};
            st0 = MFMA16(ak00, bq0, st0);
            st0 = MFMA16(ak01, bq1, st0);
            st1 = MFMA16(ak10, bq0, st1);
            st1 = MFMA16(ak11, bq1, st1);

            float p0[4], p1[4];
#pragma unroll
            for (int r = 0; r < 4; ++r) {
                p0[r] = exp2f(fmaf(st0[r], csc, -SMC));
                p1[r] = exp2f(fmaf(st1[r], csc, -SMC));
                rs_acc += p0[r] + p1[r];
            }

            union PK { __bf16 h[2]; uint32_t u; };
            uint32_t u0[4], u1[4];
#pragma unroll
            for (int r = 0; r < 4; ++r) {
                PK pk;
                pk.h[0] = (__bf16)p0[r];
                pk.h[1] = (__bf16)p1[r];
                u0[r] = (uint32_t)__shfl((int)pk.u, s0l);
                u1[r] = (uint32_t)__shfl((int)pk.u, s1l);
            }
            union PB { uint32_t u[4]; bf16x8 v; } pb;
            pb.u[0] = __builtin_amdgcn_perm(u0[1], u0[0], psel);
            pb.u[1] = __builtin_amdgcn_perm(u0[3], u0[2], psel);
            pb.u[2] = __builtin_amdgcn_perm(u1[1], u1[0], psel);
            pb.u[3] = __builtin_amdgcn_perm(u1[3], u1[2], psel);

            // PV from LDS V^T (swizzled read): av = V^T[dc*16+c][ch*32 + g*8 ..]
#pragma unroll
            for (int dc = 0; dc < 4; ++dc) {
                bf16x8 av = *(const bf16x8*)(sV + (dc * 16 + c) * 64 +
                                             ((ch * 4 + g) ^ c7) * 8);
                acc[dc] = MFMA16(av, pb.v, acc[dc]);
            }
        }
        __syncthreads();
    }
#undef STAGE

    // lsum reduce + epilogue transpose (reuses smem; loop's last barrier done).
    rs_acc += __shfl_xor(rs_acc, 16);
    rs_acc += __shfl_xor(rs_acc, 32);
    const float inv = 1.0f / rs_acc;

#pragma unroll
    for (int dc = 0; dc < 4; ++dc) {
#pragma unroll
        for (int r = 0; r < 4; ++r)
            ep[(w * 16 + c) * 69 + dc * 16 + 4 * g + r] = acc[dc][r] * inv;
    }
    __syncthreads();

    const int orow = lane >> 2;
    const int och  = lane & 3;
    bf16x8 o0, o1;
#pragma unroll
    for (int i = 0; i < 8; ++i) {
        o0[i] = (__bf16)ep[(w * 16 + orow) * 69 + och * 16 + i];
        o1[i] = (__bf16)ep[(w * 16 + orow) * 69 + och * 16 + 8 + i];
    }
    __bf16* dst = attn_out +
        ((size_t)(bh >> 4) * NS + qt * 64 + w * 16 + orow) * NE + (bh & 15) * 64 + och * 16;
    *(bf16x8*)dst = o0;
    *(bf16x8*)(dst + 8) = o1;
}

// ---------------------------------------------------------------------------
// Kernel 4: C[M,N] = A[M,K](bf16) x W^T   (m97 structure, 128x128, BK=32)
// ---------------------------------------------------------------------------
__global__ __launch_bounds__(256) void k_gemm(const __bf16* __restrict__ A,
                                              const __bf16* __restrict__ Bw,
                                              float* __restrict__ C) {
    constexpr int K = 1024, N = 1024;
    __shared__ __bf16 As[128 * 32];
    __shared__ __bf16 Bs[128 * 32];

    const int t = threadIdx.x;
    const int lane = t & 63, w = t >> 6;
    const int g = lane >> 4, c = lane & 15;
    const int wr = w >> 1, wc = w & 1;
    const size_t row0 = (size_t)blockIdx.x * 128;
    const size_t col0 = (size_t)blockIdx.y * 128;

    const char* Ag = (const char*)(A + row0 * K);
    const char* Bg = (const char*)(Bw + col0 * K);
    char* AsB = (char*)As;
    char* BsB = (char*)Bs;
    const int srow  = t >> 2;
    const int sbyte = (t & 3) * 16;

    f32x4 acc[4][4];
#pragma unroll
    for (int m = 0; m < 4; ++m)
#pragma unroll
        for (int n = 0; n < 4; ++n) acc[m][n] = (f32x4){0.f, 0.f, 0.f, 0.f};

    for (int kb = 0; kb < K; kb += 32) {
        gload_lds16(Ag + (size_t)srow * (K * 2) + kb * 2 + sbyte, AsB + t * 16);
        gload_lds16(Ag + (size_t)(srow + 64) * (K * 2) + kb * 2 + sbyte, AsB + 4096 + t * 16);
        gload_lds16(Bg + (size_t)srow * (K * 2) + kb * 2 + sbyte, BsB + t * 16);
        gload_lds16(Bg + (size_t)(srow + 64) * (K * 2) + kb * 2 + sbyte, BsB + 4096 + t * 16);
        __syncthreads();

        bf16x8 a[4], b[4];
#pragma unroll
        for (int m = 0; m < 4; ++m)
            a[m] = *(const bf16x8*)(As + (wr * 64 + m * 16 + c) * 32 + g * 8);
#pragma unroll
        for (int n = 0; n < 4; ++n)
            b[n] = *(const bf16x8*)(Bs + (wc * 64 + n * 16 + c) * 32 + g * 8);
#pragma unroll
        for (int m = 0; m < 4; ++m)
#pragma unroll
            for (int n = 0; n < 4; ++n) acc[m][n] = MFMA16(a[m], b[n], acc[m][n]);
        __syncthreads();
    }

#pragma unroll
    for (int m = 0; m < 4; ++m)
#pragma unroll
        for (int n = 0; n < 4; ++n)
#pragma unroll
            for (int r = 0; r < 4; ++r)
                C[(row0 + wr * 64 + m * 16 + 4 * g + r) * N + col0 + wc * 64 + n * 16 + c] =
                    acc[m][n][r];
}

// ---------------------------------------------------------------------------
extern "C" void kernel_launch(void* const* d_in, const int* in_sizes, int n_in,
                              void* d_out, int out_size, void* d_ws, size_t ws_size,
                              hipStream_t stream) {
    const float* x     = (const float*)d_in[0];
    const float* theta = (const float*)d_in[1];
    const float* W     = (const float*)d_in[2];
    float* out = (float*)d_out;

    char* ws = (char*)d_ws;
    __bf16* proj  = (__bf16*)(ws);
    __bf16* projT = (__bf16*)(ws + 16777216);
    __bf16* Wb    = (__bf16*)(ws + 33554432);
    __bf16* ao    = (__bf16*)(ws + 35651584);

    k_proj<<<NB * NH * (NS / 64), 256, 0, stream>>>(x, theta, proj, projT);
    k_cvtW<<<(NE * NE / 4) / 256, 256, 0, stream>>>(W, Wb);
    k_attn<<<NB * NH * (NS / 64), 256, 0, stream>>>(proj, projT, ao);
    dim3 gg(NB * NS / 128, NE / 128);
    k_gemm<<<gg, 256, 0, stream>>>(ao, Wb, out);
}

// Round 4
// 103.893 us; speedup vs baseline: 2.9201x; 1.1840x over previous
//
#include <hip/hip_runtime.h>
#include <hip/hip_bf16.h>
#include <stdint.h>

typedef float  f32x4   __attribute__((ext_vector_type(4)));
typedef float  f32x16  __attribute__((ext_vector_type(16)));
typedef __bf16 bf16x8  __attribute__((ext_vector_type(8)));
typedef __bf16 bf16x4  __attribute__((ext_vector_type(4)));

static constexpr int NB = 8, NS = 1024, NE = 1024, NH = 16;

#define MFMA16(a, b, c) __builtin_amdgcn_mfma_f32_16x16x32_bf16((a), (b), (c), 0, 0, 0)
#define MFMA32(a, b, c) __builtin_amdgcn_mfma_f32_32x32x16_bf16((a), (b), (c), 0, 0, 0)

__device__ __forceinline__ void gload_lds16(const void* g, void* l) {
    __builtin_amdgcn_global_load_lds(
        (const __attribute__((address_space(1))) void*)g,
        (__attribute__((address_space(3))) void*)l, 16, 0, 0);
}

__device__ __forceinline__ uint32_t cvt_pk_bf16(float lo, float hi) {
    uint32_t r;
    asm("v_cvt_pk_bf16_f32 %0, %1, %2" : "=v"(r) : "v"(lo), "v"(hi));
    return r;
}
// Swap upper 32 lanes of a with lower 32 lanes of b (in place).
__device__ __forceinline__ void pl32swap(uint32_t& a, uint32_t& b) {
    asm volatile("v_permlane32_swap_b32 %0, %1" : "+v"(a), "+v"(b));
}

// ---------------------------------------------------------------------------
// Kernel 1: proj = cos(x + theta), dual layout.
// ---------------------------------------------------------------------------
__global__ __launch_bounds__(256) void k_proj(const float* __restrict__ x,
                                              const float* __restrict__ theta,
                                              __bf16* __restrict__ proj,
                                              __bf16* __restrict__ projT) {
    __shared__ float sm[64][65];
    const int bid  = blockIdx.x;
    const int bh   = bid >> 4;
    const int st0  = (bid & 15) << 6;
    const int b    = bh >> 4, h = bh & 15;
    const int t    = threadIdx.x;
    const int srow = t >> 2;
    const int j4   = t & 3;

    const float* xrow = x + ((size_t)(b * NS + st0 + srow)) * NE + h * 64;
    __bf16* prow = proj + ((size_t)bh * NS + st0 + srow) * 64;

#pragma unroll
    for (int k = 0; k < 4; ++k) {
        const int d = k * 16 + j4 * 4;
        float4 xv = *(const float4*)(xrow + d);
        float4 tv = *(const float4*)(theta + d);
        float c0 = __cosf(xv.x + tv.x);
        float c1 = __cosf(xv.y + tv.y);
        float c2 = __cosf(xv.z + tv.z);
        float c3 = __cosf(xv.w + tv.w);
        bf16x4 pv = {(__bf16)c0, (__bf16)c1, (__bf16)c2, (__bf16)c3};
        *(bf16x4*)(prow + d) = pv;
        sm[d + 0][srow] = c0;
        sm[d + 1][srow] = c1;
        sm[d + 2][srow] = c2;
        sm[d + 3][srow] = c3;
    }
    __syncthreads();

    const int drow = t >> 2;
    bf16x8 o0, o1;
#pragma unroll
    for (int i = 0; i < 8; ++i) {
        o0[i] = (__bf16)sm[drow][j4 * 16 + i];
        o1[i] = (__bf16)sm[drow][j4 * 16 + 8 + i];
    }
    __bf16* dst = projT + ((size_t)bh * 64 + drow) * NS + st0 + j4 * 16;
    *(bf16x8*)dst = o0;
    *(bf16x8*)(dst + 8) = o1;
}

// ---------------------------------------------------------------------------
// Kernel 2: W (f32 [E,E]) -> bf16
// ---------------------------------------------------------------------------
__global__ __launch_bounds__(256) void k_cvtW(const float* __restrict__ W,
                                              __bf16* __restrict__ Wb) {
    const int i = (blockIdx.x * 256 + threadIdx.x) * 4;
    float4 v = *(const float4*)(W + i);
    bf16x4 o = {(__bf16)v.x, (__bf16)v.y, (__bf16)v.z, (__bf16)v.w};
    *(bf16x4*)(Wb + i) = o;
}

// ---------------------------------------------------------------------------
// Kernel 3: flash attention, 32x32x16 MFMA, T12 in-register softmax.
//   Block = 4 waves x QBLK 64 (two 32-q tiles) = 256 q-rows. Grid = 512.
//   KVBLK=64, dbuf LDS K[64][64] / V^T[64][64], XOR-swizzled chunks.
//   Swapped QK^T: st = mfma32(A=K, B=Q) -> lane holds S^T[32 k][q=lane&31].
//   Fixed-shift softmax (|scores|<=8), P->PV-B-fragment via cvt_pk + permlane.
// ---------------------------------------------------------------------------
__global__ __launch_bounds__(256, 2) void k_attn(const __bf16* __restrict__ proj,
                                                 const __bf16* __restrict__ projT,
                                                 __bf16* __restrict__ attn_out) {
    __shared__ __align__(16) char smem[32768];
    __bf16* const smK0 = (__bf16*)(smem);
    __bf16* const smV0 = (__bf16*)(smem + 8192);
    __bf16* const smK1 = (__bf16*)(smem + 16384);
    __bf16* const smV1 = (__bf16*)(smem + 24576);

    const int bid  = blockIdx.x;     // 0..511
    const int bh   = bid >> 2;       // b*16 + h
    const int qblk = bid & 3;
    const int t    = threadIdx.x;
    const int w    = t >> 6;
    const int lane = t & 63;
    const int hi   = lane >> 5;      // 0..1
    const int l5   = lane & 31;      // 0..31
    const int l7   = l5 & 7;
    const int qw   = qblk * 256 + w * 64;   // wave q-base (64 rows)

    const __bf16* P  = proj  + (size_t)bh * NS * 64;
    const __bf16* PT = projT + (size_t)bh * 64 * NS;

    // Q fragments (B operand of mfma32): lane holds Q[q = base + l5][d = ds*16 + 8*hi + i]
    bf16x8 bq[2][4];
#pragma unroll
    for (int q01 = 0; q01 < 2; ++q01)
#pragma unroll
        for (int d = 0; d < 4; ++d)
            bq[q01][d] = *(const bf16x8*)(P + (size_t)(qw + q01 * 32 + l5) * 64 + d * 16 + hi * 8);

    // Staging: thread t -> LDS row r = pass*32 + (t>>3), chunk j = t&7 (linear dest);
    // global source chunk = j ^ (r&7).
    const int srow  = t >> 3;
    const int sjsrc = (t & 7) ^ (srow & 7);
    char* const dK0 = (char*)smK0 + t * 16;
    char* const dV0 = (char*)smV0 + t * 16;
    char* const dK1 = (char*)smK1 + t * 16;
    char* const dV1 = (char*)smV1 + t * 16;

#define STAGE(kvoff, dk, dv)                                                           \
    do {                                                                               \
        gload_lds16(P  + (size_t)((kvoff) + srow)      * 64 + sjsrc * 8, (dk));        \
        gload_lds16(P  + (size_t)((kvoff) + 32 + srow) * 64 + sjsrc * 8, (dk) + 4096); \
        gload_lds16(PT + (size_t)srow        * NS + (kvoff) + sjsrc * 8, (dv));        \
        gload_lds16(PT + (size_t)(32 + srow) * NS + (kvoff) + sjsrc * 8, (dv) + 4096); \
    } while (0)

    f32x16 acc0[2], acc1[2];   // [dt] for q-tile 0 / 1
#pragma unroll
    for (int dt = 0; dt < 2; ++dt) {
        acc0[dt] = (f32x16){0.f,0.f,0.f,0.f,0.f,0.f,0.f,0.f,0.f,0.f,0.f,0.f,0.f,0.f,0.f,0.f};
        acc1[dt] = (f32x16){0.f,0.f,0.f,0.f,0.f,0.f,0.f,0.f,0.f,0.f,0.f,0.f,0.f,0.f,0.f,0.f};
    }
    float rs0 = 0.f, rs1 = 0.f;
    const float csc = 0.18033688f;   // (1/sqrt(64)) * log2(e)
    const float SMC = 11.5415606f;   // 8 * log2(e): provable score bound

    STAGE(0, dK0, dV0);
    __syncthreads();

    for (int it = 0; it < 16; ++it) {
        const int cur = it & 1;
        const __bf16* sK = cur ? smK1 : smK0;
        const __bf16* sV = cur ? smV1 : smV0;
        if (it < 15) {
            if (cur) STAGE((it + 1) * 64, dK0, dV0);
            else     STAGE((it + 1) * 64, dK1, dV1);
        }

#pragma unroll
        for (int kt = 0; kt < 2; ++kt) {
            // K fragments (A operand): K[kt*32 + l5][ds*16 + 8hi + i]
            bf16x8 ak[4];
#pragma unroll
            for (int d = 0; d < 4; ++d)
                ak[d] = *(const bf16x8*)(sK + (kt * 32 + l5) * 64 + ((d * 2 + hi) ^ l7) * 8);

            f32x16 st0 = (f32x16){0.f,0.f,0.f,0.f,0.f,0.f,0.f,0.f,0.f,0.f,0.f,0.f,0.f,0.f,0.f,0.f};
            f32x16 st1 = (f32x16){0.f,0.f,0.f,0.f,0.f,0.f,0.f,0.f,0.f,0.f,0.f,0.f,0.f,0.f,0.f,0.f};
#pragma unroll
            for (int d = 0; d < 4; ++d) {
                st0 = MFMA32(ak[d], bq[0][d], st0);
                st1 = MFMA32(ak[d], bq[1][d], st1);
            }

            // softmax (fixed shift) + pack to PV B-fragments.
            // lane reg r holds S^T[k' = (r&3)+8*(r>>2)+4*hi][q]; pack pairs,
            // permlane32_swap yields frag words for kstep = 2kt, 2kt+1 directly.
            uint32_t c0[8], c1[8];
            {
                float p[16];
#pragma unroll
                for (int r = 0; r < 16; ++r) {
                    p[r] = exp2f(fmaf(st0[r], csc, -SMC));
                    rs0 += p[r];
                }
#pragma unroll
                for (int j = 0; j < 8; ++j) c0[j] = cvt_pk_bf16(p[2 * j], p[2 * j + 1]);
            }
            {
                float p[16];
#pragma unroll
                for (int r = 0; r < 16; ++r) {
                    p[r] = exp2f(fmaf(st1[r], csc, -SMC));
                    rs1 += p[r];
                }
#pragma unroll
                for (int j = 0; j < 8; ++j) c1[j] = cvt_pk_bf16(p[2 * j], p[2 * j + 1]);
            }
            pl32swap(c0[0], c0[2]); pl32swap(c0[1], c0[3]);
            pl32swap(c0[4], c0[6]); pl32swap(c0[5], c0[7]);
            pl32swap(c1[0], c1[2]); pl32swap(c1[1], c1[3]);
            pl32swap(c1[4], c1[6]); pl32swap(c1[5], c1[7]);

#pragma unroll
            for (int half = 0; half < 2; ++half) {
                const int ks = kt * 2 + half;
                union U4 { uint32_t u[4]; bf16x8 v; };
                U4 f0, f1;
#pragma unroll
                for (int j = 0; j < 4; ++j) { f0.u[j] = c0[half * 4 + j]; f1.u[j] = c1[half * 4 + j]; }
#pragma unroll
                for (int dt = 0; dt < 2; ++dt) {
                    bf16x8 av = *(const bf16x8*)(sV + (dt * 32 + l5) * 64 + ((ks * 2 + hi) ^ l7) * 8);
                    acc0[dt] = MFMA32(av, f0.v, acc0[dt]);
                    acc1[dt] = MFMA32(av, f1.v, acc1[dt]);
                }
            }
        }
        __syncthreads();
    }
#undef STAGE

    // Epilogue: wave-private LDS transpose (no barriers needed).
    // ep per wave: [32 q][33 f32] region; 4 passes (q-tile x d-tile).
    float* const epw = (float*)smem + w * (32 * 33);
    const int orow = lane >> 1;       // q within tile
    const int ohalf = lane & 1;       // 16-wide d half

#pragma unroll
    for (int q01 = 0; q01 < 2; ++q01) {
        float rs = (q01 == 0) ? rs0 : rs1;
        rs += __shfl_xor(rs, 32);
        const float inv = 1.0f / rs;
#pragma unroll
        for (int dt = 0; dt < 2; ++dt) {
            const f32x16 a = (q01 == 0) ? acc0[dt] : acc1[dt];
#pragma unroll
            for (int r = 0; r < 16; ++r)
                epw[l5 * 33 + (r & 3) + 8 * (r >> 2) + 4 * hi] = a[r] * inv;
            // wave-internal LDS ordering: compiler emits lgkmcnt wait.
            bf16x8 o0, o1;
#pragma unroll
            for (int i = 0; i < 8; ++i) {
                o0[i] = (__bf16)(epw[orow * 33 + ohalf * 16 + i]);
                o1[i] = (__bf16)(epw[orow * 33 + ohalf * 16 + 8 + i]);
            }
            // NOTE: o1 only valid when ohalf*16+8+i < 32 -> need 16 values per lane:
            // cols ohalf*16 .. ohalf*16+15 -> o0 covers 0..7, o1 covers 8..15.
            __bf16* dst = attn_out +
                ((size_t)(bh >> 4) * NS + qblk * 256 + w * 64 + q01 * 32 + orow) * NE +
                (bh & 15) * 64 + dt * 32 + ohalf * 16;
            *(bf16x8*)dst = o0;
            *(bf16x8*)(dst + 8) = o1;
        }
    }
}

// ---------------------------------------------------------------------------
// Kernel 4: C[M,N] = A[M,K](bf16) x W^T   (m97 structure, 128x128, BK=32)
// ---------------------------------------------------------------------------
__global__ __launch_bounds__(256) void k_gemm(const __bf16* __restrict__ A,
                                              const __bf16* __restrict__ Bw,
                                              float* __restrict__ C) {
    constexpr int K = 1024, N = 1024;
    __shared__ __bf16 As[128 * 32];
    __shared__ __bf16 Bs[128 * 32];

    const int t = threadIdx.x;
    const int lane = t & 63, w = t >> 6;
    const int g = lane >> 4, c = lane & 15;
    const int wr = w >> 1, wc = w & 1;
    const size_t row0 = (size_t)blockIdx.x * 128;
    const size_t col0 = (size_t)blockIdx.y * 128;

    const char* Ag = (const char*)(A + row0 * K);
    const char* Bg = (const char*)(Bw + col0 * K);
    char* AsB = (char*)As;
    char* BsB = (char*)Bs;
    const int srow  = t >> 2;
    const int sbyte = (t & 3) * 16;

    f32x4 acc[4][4];
#pragma unroll
    for (int m = 0; m < 4; ++m)
#pragma unroll
        for (int n = 0; n < 4; ++n) acc[m][n] = (f32x4){0.f, 0.f, 0.f, 0.f};

    for (int kb = 0; kb < K; kb += 32) {
        gload_lds16(Ag + (size_t)srow * (K * 2) + kb * 2 + sbyte, AsB + t * 16);
        gload_lds16(Ag + (size_t)(srow + 64) * (K * 2) + kb * 2 + sbyte, AsB + 4096 + t * 16);
        gload_lds16(Bg + (size_t)srow * (K * 2) + kb * 2 + sbyte, BsB + t * 16);
        gload_lds16(Bg + (size_t)(srow + 64) * (K * 2) + kb * 2 + sbyte, BsB + 4096 + t * 16);
        __syncthreads();

        bf16x8 a[4], b[4];
#pragma unroll
        for (int m = 0; m < 4; ++m)
            a[m] = *(const bf16x8*)(As + (wr * 64 + m * 16 + c) * 32 + g * 8);
#pragma unroll
        for (int n = 0; n < 4; ++n)
            b[n] = *(const bf16x8*)(Bs + (wc * 64 + n * 16 + c) * 32 + g * 8);
#pragma unroll
        for (int m = 0; m < 4; ++m)
#pragma unroll
            for (int n = 0; n < 4; ++n) acc[m][n] = MFMA16(a[m], b[n], acc[m][n]);
        __syncthreads();
    }

#pragma unroll
    for (int m = 0; m < 4; ++m)
#pragma unroll
        for (int n = 0; n < 4; ++n)
#pragma unroll
            for (int r = 0; r < 4; ++r)
                C[(row0 + wr * 64 + m * 16 + 4 * g + r) * N + col0 + wc * 64 + n * 16 + c] =
                    acc[m][n][r];
}

// ---------------------------------------------------------------------------
extern "C" void kernel_launch(void* const* d_in, const int* in_sizes, int n_in,
                              void* d_out, int out_size, void* d_ws, size_t ws_size,
                              hipStream_t stream) {
    const float* x     = (const float*)d_in[0];
    const float* theta = (const float*)d_in[1];
    const float* W     = (const float*)d_in[2];
    float* out = (float*)d_out;

    char* ws = (char*)d_ws;
    __bf16* proj  = (__bf16*)(ws);
    __bf16* projT = (__bf16*)(ws + 16777216);
    __bf16* Wb    = (__bf16*)(ws + 33554432);
    __bf16* ao    = (__bf16*)(ws + 35651584);

    k_proj<<<NB * NH * (NS / 64), 256, 0, stream>>>(x, theta, proj, projT);
    k_cvtW<<<(NE * NE / 4) / 256, 256, 0, stream>>>(W, Wb);
    k_attn<<<NB * NH * 4, 256, 0, stream>>>(proj, projT, ao);
    dim3 gg(NB * NS / 128, NE / 128);
    k_gemm<<<gg, 256, 0, stream>>>(ao, Wb, out);
}

// Round 5
// 84.063 us; speedup vs baseline: 3.6090x; 1.2359x over previous
//
#include <hip/hip_runtime.h>
#include <hip/hip_bf16.h>
#include <stdint.h>

typedef float  f32x4   __attribute__((ext_vector_type(4)));
typedef float  f32x16  __attribute__((ext_vector_type(16)));
typedef __bf16 bf16x8  __attribute__((ext_vector_type(8)));
typedef __bf16 bf16x4  __attribute__((ext_vector_type(4)));

static constexpr int NB = 8, NS = 1024, NE = 1024, NH = 16;

#define MFMA16(a, b, c) __builtin_amdgcn_mfma_f32_16x16x32_bf16((a), (b), (c), 0, 0, 0)
#define MFMA32(a, b, c) __builtin_amdgcn_mfma_f32_32x32x16_bf16((a), (b), (c), 0, 0, 0)

__device__ __forceinline__ void gload_lds16(const void* g, void* l) {
    __builtin_amdgcn_global_load_lds(
        (const __attribute__((address_space(1))) void*)g,
        (__attribute__((address_space(3))) void*)l, 16, 0, 0);
}

__device__ __forceinline__ uint32_t cvt_pk_bf16(float lo, float hi) {
    uint32_t r;
    asm("v_cvt_pk_bf16_f32 %0, %1, %2" : "=v"(r) : "v"(lo), "v"(hi));
    return r;
}
__device__ __forceinline__ void pl32swap(uint32_t& a, uint32_t& b) {
    asm volatile("v_permlane32_swap_b32 %0, %1" : "+v"(a), "+v"(b));
}
__device__ __forceinline__ float exp2_raw(float x) {
    float r;
    asm("v_exp_f32 %0, %1" : "=v"(r) : "v"(x));
    return r;
}

// ---------------------------------------------------------------------------
// Kernel 1: proj = cos(x + theta), dual layout.
// ---------------------------------------------------------------------------
__global__ __launch_bounds__(256) void k_proj(const float* __restrict__ x,
                                              const float* __restrict__ theta,
                                              __bf16* __restrict__ proj,
                                              __bf16* __restrict__ projT) {
    __shared__ float sm[64][65];
    const int bid  = blockIdx.x;
    const int bh   = bid >> 4;
    const int st0  = (bid & 15) << 6;
    const int b    = bh >> 4, h = bh & 15;
    const int t    = threadIdx.x;
    const int srow = t >> 2;
    const int j4   = t & 3;

    const float* xrow = x + ((size_t)(b * NS + st0 + srow)) * NE + h * 64;
    __bf16* prow = proj + ((size_t)bh * NS + st0 + srow) * 64;

#pragma unroll
    for (int k = 0; k < 4; ++k) {
        const int d = k * 16 + j4 * 4;
        float4 xv = *(const float4*)(xrow + d);
        float4 tv = *(const float4*)(theta + d);
        float c0 = __cosf(xv.x + tv.x);
        float c1 = __cosf(xv.y + tv.y);
        float c2 = __cosf(xv.z + tv.z);
        float c3 = __cosf(xv.w + tv.w);
        bf16x4 pv = {(__bf16)c0, (__bf16)c1, (__bf16)c2, (__bf16)c3};
        *(bf16x4*)(prow + d) = pv;
        sm[d + 0][srow] = c0;
        sm[d + 1][srow] = c1;
        sm[d + 2][srow] = c2;
        sm[d + 3][srow] = c3;
    }
    __syncthreads();

    const int drow = t >> 2;
    bf16x8 o0, o1;
#pragma unroll
    for (int i = 0; i < 8; ++i) {
        o0[i] = (__bf16)sm[drow][j4 * 16 + i];
        o1[i] = (__bf16)sm[drow][j4 * 16 + 8 + i];
    }
    __bf16* dst = projT + ((size_t)bh * 64 + drow) * NS + st0 + j4 * 16;
    *(bf16x8*)dst = o0;
    *(bf16x8*)(dst + 8) = o1;
}

// ---------------------------------------------------------------------------
// Kernel 2: W (f32 [E,E]) -> bf16
// ---------------------------------------------------------------------------
__global__ __launch_bounds__(256) void k_cvtW(const float* __restrict__ W,
                                              __bf16* __restrict__ Wb) {
    const int i = (blockIdx.x * 256 + threadIdx.x) * 4;
    float4 v = *(const float4*)(W + i);
    bf16x4 o = {(__bf16)v.x, (__bf16)v.y, (__bf16)v.z, (__bf16)v.w};
    *(bf16x4*)(Wb + i) = o;
}

// ---------------------------------------------------------------------------
// Kernel 3: flash attention, 32x32x16 MFMA, in-register softmax, VALU-diet:
//   - Q pre-scaled by csc = log2(e)/sqrt(64); the softmax shift constant
//     cancels in the normalization, so p = v_exp_f32(st) directly.
//   - All 16 swizzled LDS read base addresses hoisted out of the loop
//     (dbuf handled by two static pointer sets + manual 2x unroll).
//   - Tree-reduced row sums; setprio(1) around MFMA clusters.
// ---------------------------------------------------------------------------
__global__ __launch_bounds__(256, 2) void k_attn(const __bf16* __restrict__ proj,
                                                 const __bf16* __restrict__ projT,
                                                 __bf16* __restrict__ attn_out) {
    __shared__ __align__(16) char smem[32768];
    __bf16* const smK0 = (__bf16*)(smem);
    __bf16* const smV0 = (__bf16*)(smem + 8192);
    __bf16* const smK1 = (__bf16*)(smem + 16384);
    __bf16* const smV1 = (__bf16*)(smem + 24576);

    const int bid  = blockIdx.x;     // 0..511
    const int bh   = bid >> 2;       // b*16 + h
    const int qblk = bid & 3;
    const int t    = threadIdx.x;
    const int w    = t >> 6;
    const int lane = t & 63;
    const int hi   = lane >> 5;      // 0..1
    const int l5   = lane & 31;      // 0..31
    const int l7   = l5 & 7;
    const int qw   = qblk * 256 + w * 64;   // wave q-base (64 rows)

    const __bf16* P  = proj  + (size_t)bh * NS * 64;
    const __bf16* PT = projT + (size_t)bh * 64 * NS;

    const float csc = 0.18033688f;   // (1/sqrt(64)) * log2(e)

    // Q fragments (B operand), PRE-SCALED by csc.
    bf16x8 bq[2][4];
#pragma unroll
    for (int q01 = 0; q01 < 2; ++q01)
#pragma unroll
        for (int d = 0; d < 4; ++d) {
            bf16x8 v = *(const bf16x8*)(P + (size_t)(qw + q01 * 32 + l5) * 64 + d * 16 + hi * 8);
            bf16x8 o;
#pragma unroll
            for (int i = 0; i < 8; ++i) o[i] = (__bf16)((float)v[i] * csc);
            bq[q01][d] = o;
        }

    // Hoisted swizzled LDS read bases (per-lane), both dbuf copies.
    const __bf16* kP0[4];
    const __bf16* kP1[4];
    const __bf16* vP0[4];
    const __bf16* vP1[4];
#pragma unroll
    for (int d = 0; d < 4; ++d) {
        const int off = l5 * 64 + ((d * 2 + hi) ^ l7) * 8;
        kP0[d] = smK0 + off;
        kP1[d] = smK1 + off;
        vP0[d] = smV0 + off;   // d plays the role of ks for V
        vP1[d] = smV1 + off;
    }

    // Staging geometry (linear LDS dest, pre-swizzled global source).
    const int srow  = t >> 3;
    const int sjsrc = (t & 7) ^ (srow & 7);
    char* const dK0 = (char*)smK0 + t * 16;
    char* const dV0 = (char*)smV0 + t * 16;
    char* const dK1 = (char*)smK1 + t * 16;
    char* const dV1 = (char*)smV1 + t * 16;

#define STAGE(kvoff, dk, dv)                                                           \
    do {                                                                               \
        gload_lds16(P  + (size_t)((kvoff) + srow)      * 64 + sjsrc * 8, (dk));        \
        gload_lds16(P  + (size_t)((kvoff) + 32 + srow) * 64 + sjsrc * 8, (dk) + 4096); \
        gload_lds16(PT + (size_t)srow        * NS + (kvoff) + sjsrc * 8, (dv));        \
        gload_lds16(PT + (size_t)(32 + srow) * NS + (kvoff) + sjsrc * 8, (dv) + 4096); \
    } while (0)

    f32x16 acc0[2], acc1[2];
#pragma unroll
    for (int dt = 0; dt < 2; ++dt) {
        acc0[dt] = (f32x16){0.f,0.f,0.f,0.f,0.f,0.f,0.f,0.f,0.f,0.f,0.f,0.f,0.f,0.f,0.f,0.f};
        acc1[dt] = (f32x16){0.f,0.f,0.f,0.f,0.f,0.f,0.f,0.f,0.f,0.f,0.f,0.f,0.f,0.f,0.f,0.f};
    }
    float rs0 = 0.f, rs1 = 0.f;

    auto compute = [&](const __bf16* const* kR, const __bf16* const* vR) {
#pragma unroll
        for (int kt = 0; kt < 2; ++kt) {
            bf16x8 ak[4];
#pragma unroll
            for (int d = 0; d < 4; ++d)
                ak[d] = *(const bf16x8*)(kR[d] + kt * 2048);

            f32x16 st0 = (f32x16){0.f,0.f,0.f,0.f,0.f,0.f,0.f,0.f,0.f,0.f,0.f,0.f,0.f,0.f,0.f,0.f};
            f32x16 st1 = (f32x16){0.f,0.f,0.f,0.f,0.f,0.f,0.f,0.f,0.f,0.f,0.f,0.f,0.f,0.f,0.f,0.f};
            __builtin_amdgcn_s_setprio(1);
#pragma unroll
            for (int d = 0; d < 4; ++d) {
                st0 = MFMA32(ak[d], bq[0][d], st0);
                st1 = MFMA32(ak[d], bq[1][d], st1);
            }
            __builtin_amdgcn_s_setprio(0);

            uint32_t c0[8], c1[8];
            {
                float p[16];
#pragma unroll
                for (int r = 0; r < 16; ++r) p[r] = exp2_raw(st0[r]);
                rs0 += (((p[0] + p[1]) + (p[2] + p[3])) + ((p[4] + p[5]) + (p[6] + p[7]))) +
                       (((p[8] + p[9]) + (p[10] + p[11])) + ((p[12] + p[13]) + (p[14] + p[15])));
#pragma unroll
                for (int j = 0; j < 8; ++j) c0[j] = cvt_pk_bf16(p[2 * j], p[2 * j + 1]);
            }
            {
                float p[16];
#pragma unroll
                for (int r = 0; r < 16; ++r) p[r] = exp2_raw(st1[r]);
                rs1 += (((p[0] + p[1]) + (p[2] + p[3])) + ((p[4] + p[5]) + (p[6] + p[7]))) +
                       (((p[8] + p[9]) + (p[10] + p[11])) + ((p[12] + p[13]) + (p[14] + p[15])));
#pragma unroll
                for (int j = 0; j < 8; ++j) c1[j] = cvt_pk_bf16(p[2 * j], p[2 * j + 1]);
            }
            pl32swap(c0[0], c0[2]); pl32swap(c0[1], c0[3]);
            pl32swap(c0[4], c0[6]); pl32swap(c0[5], c0[7]);
            pl32swap(c1[0], c1[2]); pl32swap(c1[1], c1[3]);
            pl32swap(c1[4], c1[6]); pl32swap(c1[5], c1[7]);

#pragma unroll
            for (int half = 0; half < 2; ++half) {
                const int ks = kt * 2 + half;
                union U4 { uint32_t u[4]; bf16x8 v; };
                U4 f0, f1;
#pragma unroll
                for (int j = 0; j < 4; ++j) {
                    f0.u[j] = c0[half * 4 + j];
                    f1.u[j] = c1[half * 4 + j];
                }
                __builtin_amdgcn_s_setprio(1);
#pragma unroll
                for (int dt = 0; dt < 2; ++dt) {
                    bf16x8 av = *(const bf16x8*)(vR[ks] + dt * 2048);
                    acc0[dt] = MFMA32(av, f0.v, acc0[dt]);
                    acc1[dt] = MFMA32(av, f1.v, acc1[dt]);
                }
                __builtin_amdgcn_s_setprio(0);
            }
        }
    };

    STAGE(0, dK0, dV0);
    __syncthreads();

#pragma unroll 1
    for (int it2 = 0; it2 < 8; ++it2) {
        STAGE((2 * it2 + 1) * 64, dK1, dV1);
        compute(kP0, vP0);
        __syncthreads();
        if (it2 < 7) STAGE((2 * it2 + 2) * 64, dK0, dV0);
        compute(kP1, vP1);
        __syncthreads();
    }
#undef STAGE

    // Epilogue: wave-private LDS transpose.
    float* const epw = (float*)smem + w * (32 * 33);
    const int orow = lane >> 1;
    const int ohalf = lane & 1;

#pragma unroll
    for (int q01 = 0; q01 < 2; ++q01) {
        float rs = (q01 == 0) ? rs0 : rs1;
        rs += __shfl_xor(rs, 32);
        const float inv = 1.0f / rs;
#pragma unroll
        for (int dt = 0; dt < 2; ++dt) {
            const f32x16 a = (q01 == 0) ? acc0[dt] : acc1[dt];
#pragma unroll
            for (int r = 0; r < 16; ++r)
                epw[l5 * 33 + (r & 3) + 8 * (r >> 2) + 4 * hi] = a[r] * inv;
            bf16x8 o0, o1;
#pragma unroll
            for (int i = 0; i < 8; ++i) {
                o0[i] = (__bf16)(epw[orow * 33 + ohalf * 16 + i]);
                o1[i] = (__bf16)(epw[orow * 33 + ohalf * 16 + 8 + i]);
            }
            __bf16* dst = attn_out +
                ((size_t)(bh >> 4) * NS + qblk * 256 + w * 64 + q01 * 32 + orow) * NE +
                (bh & 15) * 64 + dt * 32 + ohalf * 16;
            *(bf16x8*)dst = o0;
            *(bf16x8*)(dst + 8) = o1;
        }
    }
}

// ---------------------------------------------------------------------------
// Kernel 4: C[M,N] = A[M,K](bf16) x W^T   (m97 structure, 128x128, BK=32)
// ---------------------------------------------------------------------------
__global__ __launch_bounds__(256) void k_gemm(const __bf16* __restrict__ A,
                                              const __bf16* __restrict__ Bw,
                                              float* __restrict__ C) {
    constexpr int K = 1024, N = 1024;
    __shared__ __bf16 As[128 * 32];
    __shared__ __bf16 Bs[128 * 32];

    const int t = threadIdx.x;
    const int lane = t & 63, w = t >> 6;
    const int g = lane >> 4, c = lane & 15;
    const int wr = w >> 1, wc = w & 1;
    const size_t row0 = (size_t)blockIdx.x * 128;
    const size_t col0 = (size_t)blockIdx.y * 128;

    const char* Ag = (const char*)(A + row0 * K);
    const char* Bg = (const char*)(Bw + col0 * K);
    char* AsB = (char*)As;
    char* BsB = (char*)Bs;
    const int srow  = t >> 2;
    const int sbyte = (t & 3) * 16;

    f32x4 acc[4][4];
#pragma unroll
    for (int m = 0; m < 4; ++m)
#pragma unroll
        for (int n = 0; n < 4; ++n) acc[m][n] = (f32x4){0.f, 0.f, 0.f, 0.f};

    for (int kb = 0; kb < K; kb += 32) {
        gload_lds16(Ag + (size_t)srow * (K * 2) + kb * 2 + sbyte, AsB + t * 16);
        gload_lds16(Ag + (size_t)(srow + 64) * (K * 2) + kb * 2 + sbyte, AsB + 4096 + t * 16);
        gload_lds16(Bg + (size_t)srow * (K * 2) + kb * 2 + sbyte, BsB + t * 16);
        gload_lds16(Bg + (size_t)(srow + 64) * (K * 2) + kb * 2 + sbyte, BsB + 4096 + t * 16);
        __syncthreads();

        bf16x8 a[4], b[4];
#pragma unroll
        for (int m = 0; m < 4; ++m)
            a[m] = *(const bf16x8*)(As + (wr * 64 + m * 16 + c) * 32 + g * 8);
#pragma unroll
        for (int n = 0; n < 4; ++n)
            b[n] = *(const bf16x8*)(Bs + (wc * 64 + n * 16 + c) * 32 + g * 8);
#pragma unroll
        for (int m = 0; m < 4; ++m)
#pragma unroll
            for (int n = 0; n < 4; ++n) acc[m][n] = MFMA16(a[m], b[n], acc[m][n]);
        __syncthreads();
    }

#pragma unroll
    for (int m = 0; m < 4; ++m)
#pragma unroll
        for (int n = 0; n < 4; ++n)
#pragma unroll
            for (int r = 0; r < 4; ++r)
                C[(row0 + wr * 64 + m * 16 + 4 * g + r) * N + col0 + wc * 64 + n * 16 + c] =
                    acc[m][n][r];
}

// ---------------------------------------------------------------------------
extern "C" void kernel_launch(void* const* d_in, const int* in_sizes, int n_in,
                              void* d_out, int out_size, void* d_ws, size_t ws_size,
                              hipStream_t stream) {
    const float* x     = (const float*)d_in[0];
    const float* theta = (const float*)d_in[1];
    const float* W     = (const float*)d_in[2];
    float* out = (float*)d_out;

    char* ws = (char*)d_ws;
    __bf16* proj  = (__bf16*)(ws);
    __bf16* projT = (__bf16*)(ws + 16777216);
    __bf16* Wb    = (__bf16*)(ws + 33554432);
    __bf16* ao    = (__bf16*)(ws + 35651584);

    k_proj<<<NB * NH * (NS / 64), 256, 0, stream>>>(x, theta, proj, projT);
    k_cvtW<<<(NE * NE / 4) / 256, 256, 0, stream>>>(W, Wb);
    k_attn<<<NB * NH * 4, 256, 0, stream>>>(proj, projT, ao);
    dim3 gg(NB * NS / 128, NE / 128);
    k_gemm<<<gg, 256, 0, stream>>>(ao, Wb, out);
}